// Round 6
// baseline (1937.976 us; speedup 1.0000x reference)
//
#include <hip/hip_runtime.h>
#include <math.h>

#define NBF 4104             // B*F = 8*513
#define XT_FLOATS 16809984   // 8*513*8*512

// Static device scratch; fully overwritten before read each call -> deterministic.
__device__ float d_partials[NBF];
__device__ float d_scales[8];

// Phase-A accumulation for one row-group. g0 rows {0,3,5,6}, g1 rows {1,2,4,7}:
// 4 diagonals + 14 off-diagonal complex entries each (balanced 18/18 split of the
// 36 Hermitian entries). 32 accumulator floats per thread (vs 64 monolithic),
// which is what keeps VGPR under the 170 cap without spilling.
template<int G>
__device__ __forceinline__ void phaseA_accum(
    const float2* __restrict__ sx,    // packed (re,im) [8][512]
    const float*  __restrict__ rrow,  // &r[bf][k][ts]
    const int ts,
    float* __restrict__ accd, float* __restrict__ accr, float* __restrict__ acci)
{
    constexpr int rows[4] = {G ? 1 : 0, G ? 2 : 3, G ? 4 : 5, G ? 7 : 6};
    float rb[8];
    #pragma unroll
    for (int i = 0; i < 8; ++i) rb[i] = rrow[i << 4];
    #pragma unroll
    for (int c = 0; c < 4; ++c) {
        float rb2[8];
        if (c < 3) {
            #pragma unroll
            for (int i = 0; i < 8; ++i) rb2[i] = rrow[(((c + 1) << 3) + i) << 4];
        }
        #pragma unroll
        for (int i = 0; i < 8; ++i) {
            const int t = ts + (((c << 3) + i) << 4);
            const float rw = fmaxf(rb[i], 1e-3f);
            float2 xv[8];
            #pragma unroll
            for (int n = 0; n < 8; ++n) xv[n] = sx[(n << 9) + t];
            int p = 0;
            #pragma unroll
            for (int ri = 0; ri < 4; ++ri) {
                const int m = rows[ri];
                const float yr = rw * xv[m].x, yi = rw * xv[m].y;
                accd[ri] += yr * xv[m].x + yi * xv[m].y;
                #pragma unroll
                for (int n = m + 1; n < 8; ++n, ++p) {
                    accr[p] += yr * xv[n].x + yi * xv[n].y;
                    acci[p] += yi * xv[n].x - yr * xv[n].y;
                }
            }
        }
        if (c < 3) {
            #pragma unroll
            for (int i = 0; i < 8; ++i) rb[i] = rb2[i];
        }
    }
}

template<int G>
__device__ __forceinline__ void phaseA_write(
    float2 (*s_V)[8][9], const int k,
    const float* __restrict__ accd, const float* __restrict__ accr,
    const float* __restrict__ acci)
{
    constexpr int rows[4] = {G ? 1 : 0, G ? 2 : 3, G ? 4 : 5, G ? 7 : 6};
    const float invT = 1.0f / 512.0f;
    int p = 0;
    #pragma unroll
    for (int ri = 0; ri < 4; ++ri) {
        const int m = rows[ri];
        s_V[k][m][m] = make_float2(accd[ri] * invT, 0.f);   // +e added in diag-fix pass
        #pragma unroll
        for (int n = m + 1; n < 8; ++n, ++p) {
            const float vr = accr[p] * invT, vi = acci[p] * invT;
            s_V[k][m][n] = make_float2(vr,  vi);
            s_V[k][n][m] = make_float2(vr, -vi);
        }
    }
}

// (256,3): VGPR cap 170 (>= ~110 natural usage -> no spill; round 4's (256,4)
// collapsed VGPR to 64 and cost 570 MB of spill traffic). Guarantees >=3 blocks/CU.
__global__ __launch_bounds__(256, 3) void iss_main(
    const float* __restrict__ g_r,
    const float* __restrict__ g_xre,
    const float* __restrict__ g_xim,
    const float* __restrict__ g_Qre,
    const float* __restrict__ g_Qim,
    float* __restrict__ g_out,
    const int qmode,        // 2 = interleaved re,im pairs; 1 = real part only
    const int xt_off)       // float offset where the xt region begins
{
    __shared__ float2 s_x[8][512];     // packed (re,im), 32 KB
    __shared__ float2 s_V[8][8][9];    // padded row stride
    __shared__ float2 s_Q[8][8];
    __shared__ float  s_part[4];

    const int tid = threadIdx.x;
    const int bf  = blockIdx.x;
    const size_t base = (size_t)bf * 4096;

    // ---- stage x into packed LDS (float4 global loads, coalesced); Q into s_Q ----
    {
        const float4* xr4 = (const float4*)(g_xre + base);
        const float4* xi4 = (const float4*)(g_xim + base);
        float4* sx4 = (float4*)&s_x[0][0];
        #pragma unroll
        for (int i = 0; i < 4; ++i) {
            const int idx = tid + (i << 8);
            const float4 xr = xr4[idx], xi = xi4[idx];
            sx4[2*idx]   = make_float4(xr.x, xi.x, xr.y, xi.y);
            sx4[2*idx+1] = make_float4(xr.z, xi.z, xr.w, xi.w);
        }
        if (tid < 64)
            s_Q[tid>>3][tid&7] = make_float2(g_Qre[(size_t)bf*64 + tid],
                                             g_Qim[(size_t)bf*64 + tid]);
    }
    __syncthreads();

    // ---- phase A: V[k] = (1/T) sum_t max(r,1e-3) x x^H, row-group split ----
    const int ts = tid & 15;          // t-slice within (g,k) group
    const int k  = (tid >> 4) & 7;
    const int g  = tid >> 7;          // wave-uniform (waves 0,1 -> g0; 2,3 -> g1)

    float accd[4] = {0,0,0,0};
    float accr[14], acci[14];
    #pragma unroll
    for (int p = 0; p < 14; ++p) { accr[p] = 0.f; acci[p] = 0.f; }

    const float* rrow = g_r + base + (k << 9) + ts;
    if (g == 0) phaseA_accum<0>(&s_x[0][0], rrow, ts, accd, accr, acci);
    else        phaseA_accum<1>(&s_x[0][0], rrow, ts, accd, accr, acci);

    // reduce across the 16 lanes sharing (g,k): xor offsets 1..8 stay in-group
    #pragma unroll
    for (int q = 0; q < 4; ++q) {
        #pragma unroll
        for (int off = 1; off < 16; off <<= 1) accd[q] += __shfl_xor(accd[q], off, 64);
    }
    #pragma unroll
    for (int p = 0; p < 14; ++p) {
        #pragma unroll
        for (int off = 1; off < 16; off <<= 1) accr[p] += __shfl_xor(accr[p], off, 64);
        #pragma unroll
        for (int off = 1; off < 16; off <<= 1) acci[p] += __shfl_xor(acci[p], off, 64);
    }

    if (ts == 0) {
        if (g == 0) phaseA_write<0>(s_V, k, accd, accr, acci);
        else        phaseA_write<1>(s_V, k, accd, accr, acci);
    }
    __syncthreads();

    // ---- diag fix: add max(trace,1)*EPS (trace spans both row-groups) ----
    if (tid < 64) {
        const int kq = tid >> 3, mq = tid & 7;
        const float dv = s_V[kq][mq][mq].x;
        float tr = dv;
        #pragma unroll
        for (int off = 1; off < 8; off <<= 1) tr += __shfl_xor(tr, off, 64);
        s_V[kq][mq][mq].x = dv + fmaxf(tr, 1.0f) * 1e-6f;
    }
    __syncthreads();

    // ---- phase B: wave-synchronous, zero barriers, all waves redundant ----
    {
        const int lane = tid & 63;
        const int kp = lane >> 3, mm = lane & 7;
        float vRr[8], vRi[8];
        #pragma unroll
        for (int n = 0; n < 8; ++n) {
            const float2 V = s_V[kp][mm][n];
            vRr[n] = V.x; vRi[n] = V.y;
        }
        const float2 Q0 = s_Q[kp][mm];
        float qre = Q0.x, qim = Q0.y;

        #pragma unroll
        for (int step = 0; step < 16; ++step) {
            const int kk = step & 7;
            float qnr[8], qni[8];
            #pragma unroll
            for (int n = 0; n < 8; ++n) {
                qnr[n] = __shfl(qre, (kk<<3)+n, 64);
                qni[n] = __shfl(qim, (kk<<3)+n, 64);
            }
            const float qmr = __shfl(qre, (kk<<3)+mm, 64);
            const float qmi = __shfl(qim, (kk<<3)+mm, 64);

            float vqr = 0.f, vqi = 0.f;
            #pragma unroll
            for (int n = 0; n < 8; ++n) {
                vqr += vRr[n]*qnr[n] + vRi[n]*qni[n];   // V * conj(q)
                vqi += vRi[n]*qnr[n] - vRr[n]*qni[n];
            }
            float p   = qmr*vqr - qmi*vqi;              // Re(q_m * Vq_m)
            float tre = qre*vqr - qim*vqi;              // Q_own * Vq_own
            float tim = qre*vqi + qim*vqr;
            #pragma unroll
            for (int off = 1; off < 8; off <<= 1) {
                p   += __shfl_xor(p,   off, 64);
                tre += __shfl_xor(tre, off, 64);
                tim += __shfl_xor(tim, off, 64);
            }
            const float qvq = fmaxf(p, 1e-6f);
            float vr_, vi_;
            if (kp == kk) { vr_ = 1.0f - rsqrtf(qvq); vi_ = 0.f; }
            else { const float inv = 1.0f / qvq; vr_ = tre*inv; vi_ = tim*inv; }
            qre -= vr_*qmr - vi_*qmi;
            qim -= vr_*qmi + vi_*qmr;
        }

        if (tid < 64) {
            s_Q[kp][mm] = make_float2(qre, qim);
            if (qmode == 2) {
                g_out[(size_t)bf*128 + tid*2]     = qre;
                g_out[(size_t)bf*128 + tid*2 + 1] = qim;
            } else {
                g_out[(size_t)bf*64 + tid] = qre;
            }
        }
    }
    __syncthreads();

    // ---- phase C: xt = |Q x|^2 (unnormalized), float4 I/O, block partial sum ----
    float lsum = 0.f;
    float* out_xt = g_out + xt_off;
    const float2* sx = &s_x[0][0];
    #pragma unroll
    for (int j = 0; j < 4; ++j) {
        const int idx4 = tid + (j << 8);       // 1024 output float4 slots
        const int m  = idx4 >> 7;
        const int tq = (idx4 & 127) << 2;      // 4 consecutive t
        float qxr[4] = {0,0,0,0}, qxi[4] = {0,0,0,0};
        #pragma unroll
        for (int n = 0; n < 8; ++n) {
            const float2 Qv = s_Q[m][n];
            const float4 a = *(const float4*)&sx[(n << 9) + tq];      // t: tq, tq+1
            const float4 b = *(const float4*)&sx[(n << 9) + tq + 2];  // t: tq+2, tq+3
            qxr[0] += Qv.x*a.x - Qv.y*a.y;  qxi[0] += Qv.x*a.y + Qv.y*a.x;
            qxr[1] += Qv.x*a.z - Qv.y*a.w;  qxi[1] += Qv.x*a.w + Qv.y*a.z;
            qxr[2] += Qv.x*b.x - Qv.y*b.y;  qxi[2] += Qv.x*b.y + Qv.y*b.x;
            qxr[3] += Qv.x*b.z - Qv.y*b.w;  qxi[3] += Qv.x*b.w + Qv.y*b.z;
        }
        float4 pw;
        pw.x = qxr[0]*qxr[0] + qxi[0]*qxi[0];
        pw.y = qxr[1]*qxr[1] + qxi[1]*qxi[1];
        pw.z = qxr[2]*qxr[2] + qxi[2]*qxi[2];
        pw.w = qxr[3]*qxr[3] + qxi[3]*qxi[3];
        *(float4*)&out_xt[base + ((size_t)idx4 << 2)] = pw;
        lsum += pw.x + pw.y + pw.z + pw.w;
    }
    #pragma unroll
    for (int off = 32; off >= 1; off >>= 1) lsum += __shfl_xor(lsum, off, 64);
    if ((tid & 63) == 0) s_part[tid >> 6] = lsum;
    __syncthreads();
    if (tid == 0) d_partials[bf] = s_part[0] + s_part[1] + s_part[2] + s_part[3];
}

__global__ __launch_bounds__(256) void iss_scale()
{
    const int b = blockIdx.x, tid = threadIdx.x;
    __shared__ float sp[4];
    float s = 0.f;
    for (int i = tid; i < 513; i += 256) s += d_partials[b*513 + i];
    #pragma unroll
    for (int off = 32; off >= 1; off >>= 1) s += __shfl_xor(s, off, 64);
    if ((tid & 63) == 0) sp[tid >> 6] = s;
    __syncthreads();
    if (tid == 0) d_scales[b] = (sp[0]+sp[1]+sp[2]+sp[3]) / (513.0f * 8.0f * 512.0f);
}

__global__ __launch_bounds__(256) void iss_norm(
    float* __restrict__ g_out,
    const int nq4,     // Q region in float4s  (= xt_off/4)
    const int qb4,     // float4s per batch in Q region
    const int nt4)     // total float4s (= out_size/4)
{
    float4* o4 = (float4*)g_out;
    for (int i = blockIdx.x*256 + threadIdx.x; i < nt4; i += gridDim.x*256) {
        float s;
        if (i < nq4) {
            const int b = i / qb4;
            s = rsqrtf(fmaxf(d_scales[b], 1e-6f));
        } else {
            const int j = i - nq4;
            const int b = j / 525312;          // xt float4s per batch
            s = 1.0f / d_scales[b];
        }
        float4 v = o4[i];
        v.x *= s; v.y *= s; v.z *= s; v.w *= s;
        o4[i] = v;
    }
}

extern "C" void kernel_launch(void* const* d_in, const int* in_sizes, int n_in,
                              void* d_out, int out_size, void* d_ws, size_t ws_size,
                              hipStream_t stream) {
    const float* r   = (const float*)d_in[0];
    const float* xre = (const float*)d_in[1];
    const float* xim = (const float*)d_in[2];
    const float* Qre = (const float*)d_in[3];
    const float* Qim = (const float*)d_in[4];
    float* out = (float*)d_out;

    const int q_floats = out_size - XT_FLOATS;
    const int qmode  = (q_floats >= 525312) ? 2 : 1;
    const int xt_off = (qmode == 2) ? 525312 : 262656;
    const int nq4 = xt_off / 4;
    const int qb4 = xt_off / (4 * 8);
    const int nt4 = nq4 + XT_FLOATS / 4;

    iss_main <<<NBF, 256, 0, stream>>>(r, xre, xim, Qre, Qim, out, qmode, xt_off);
    iss_scale<<<8,   256, 0, stream>>>();
    iss_norm <<<4096,256, 0, stream>>>(out, nq4, qb4, nt4);
}

// Round 7
// 1801.482 us; speedup vs baseline: 1.0758x; 1.0758x over previous
//
#include <hip/hip_runtime.h>
#include <math.h>

#define NBF 4104             // B*F = 8*513
#define XT_FLOATS 16809984   // 8*513*8*512

// Static device scratch; fully overwritten before read each call -> deterministic.
__device__ float d_partials[NBF];
__device__ float d_scales[8];

// Phase-A macros. All accumulators are PLAIN LOCALS with compile-time indices:
// round 6 passed them by pointer into a helper -> SROA failed -> 6 GB scratch
// traffic. Everything must stay inline in the kernel body.
#define DIAG(Q,M)    yr = rw*xv[M].x; yi = rw*xv[M].y; \
                     accd[Q] += yr*xv[M].x + yi*xv[M].y;
#define CROSS(P,M,N) accr[P] += yr*xv[N].x + yi*xv[N].y; \
                     acci[P] += yi*xv[N].x - yr*xv[N].y;
#define VSTD(Q,M)    s_V[k][M][M] = make_float2(accd[Q]*invT, 0.f);
#define VSTO(P,M,N)  { const float vr=accr[P]*invT, vi=acci[P]*invT; \
                       s_V[k][M][N] = make_float2(vr,  vi);          \
                       s_V[k][N][M] = make_float2(vr, -vi); }

// (256,4): VGPR cap 128 vs ~95 estimated live (32 acc + 32 rbuf + 16 xv + addr).
// Round 4's failure was cap 64 vs need 96; here the margin is ~1.3x.
__global__ __launch_bounds__(256, 4) void iss_main(
    const float* __restrict__ g_r,
    const float* __restrict__ g_xre,
    const float* __restrict__ g_xim,
    const float* __restrict__ g_Qre,
    const float* __restrict__ g_Qim,
    float* __restrict__ g_out,
    const int qmode,        // 2 = interleaved re,im pairs; 1 = real part only
    const int xt_off)       // float offset where the xt region begins
{
    __shared__ float2 s_x[8][512];     // packed (re,im), 32 KB
    __shared__ float2 s_V[8][8][9];    // padded row stride
    __shared__ float2 s_Q[8][8];
    __shared__ float  s_part[4];

    const int tid = threadIdx.x;
    const int bf  = blockIdx.x;
    const size_t base = (size_t)bf * 4096;

    // ---- stage x into packed LDS (float4 global loads, coalesced); Q into s_Q ----
    {
        const float4* xr4 = (const float4*)(g_xre + base);
        const float4* xi4 = (const float4*)(g_xim + base);
        float4* sx4 = (float4*)&s_x[0][0];
        #pragma unroll
        for (int i = 0; i < 4; ++i) {
            const int idx = tid + (i << 8);
            const float4 xr = xr4[idx], xi = xi4[idx];
            sx4[2*idx]   = make_float4(xr.x, xi.x, xr.y, xi.y);
            sx4[2*idx+1] = make_float4(xr.z, xi.z, xr.w, xi.w);
        }
        if (tid < 64)
            s_Q[tid>>3][tid&7] = make_float2(g_Qre[(size_t)bf*64 + tid],
                                             g_Qim[(size_t)bf*64 + tid]);
    }
    __syncthreads();

    // ---- phase A: V[k] = (1/T) sum_t max(r,1e-3) x x^H, row-group split ----
    // 16 lanes per (g,k) group; g0 owns rows {0,3,5,6}, g1 rows {1,2,4,7}
    // (14 off-diagonal complex entries + 4 diagonals each).
    const int ts = tid & 15;
    const int k  = (tid >> 4) & 7;
    const int g  = tid >> 7;          // wave-uniform

    float accd[4] = {0,0,0,0};
    float accr[14], acci[14];
    #pragma unroll
    for (int p = 0; p < 14; ++p) { accr[p] = 0.f; acci[p] = 0.f; }

    {
        // prefetch all 32 r values (stride 16 floats) -> global latency amortized
        float rbuf[32];
        const float* rrow = g_r + base + (k << 9) + ts;
        #pragma unroll
        for (int i = 0; i < 32; ++i) rbuf[i] = rrow[i << 4];

        if (g == 0) {
            #pragma unroll
            for (int i = 0; i < 32; ++i) {
                const int t = ts + (i << 4);
                const float rw = fmaxf(rbuf[i], 1e-3f);
                float2 xv[8];
                #pragma unroll
                for (int n = 0; n < 8; ++n) xv[n] = s_x[n][t];
                float yr, yi;
                DIAG(0,0) CROSS(0,0,1) CROSS(1,0,2) CROSS(2,0,3) CROSS(3,0,4)
                          CROSS(4,0,5) CROSS(5,0,6) CROSS(6,0,7)
                DIAG(1,3) CROSS(7,3,4) CROSS(8,3,5) CROSS(9,3,6) CROSS(10,3,7)
                DIAG(2,5) CROSS(11,5,6) CROSS(12,5,7)
                DIAG(3,6) CROSS(13,6,7)
            }
        } else {
            #pragma unroll
            for (int i = 0; i < 32; ++i) {
                const int t = ts + (i << 4);
                const float rw = fmaxf(rbuf[i], 1e-3f);
                float2 xv[8];
                #pragma unroll
                for (int n = 0; n < 8; ++n) xv[n] = s_x[n][t];
                float yr, yi;
                DIAG(0,1) CROSS(0,1,2) CROSS(1,1,3) CROSS(2,1,4) CROSS(3,1,5)
                          CROSS(4,1,6) CROSS(5,1,7)
                DIAG(1,2) CROSS(6,2,3) CROSS(7,2,4) CROSS(8,2,5) CROSS(9,2,6)
                          CROSS(10,2,7)
                DIAG(2,4) CROSS(11,4,5) CROSS(12,4,6) CROSS(13,4,7)
                DIAG(3,7)
            }
        }
    }

    // reduce across the 16 lanes sharing (g,k): xor offsets 1..8 stay in-group
    #pragma unroll
    for (int q = 0; q < 4; ++q) {
        #pragma unroll
        for (int off = 1; off < 16; off <<= 1) accd[q] += __shfl_xor(accd[q], off, 64);
    }
    #pragma unroll
    for (int p = 0; p < 14; ++p) {
        #pragma unroll
        for (int off = 1; off < 16; off <<= 1) accr[p] += __shfl_xor(accr[p], off, 64);
        #pragma unroll
        for (int off = 1; off < 16; off <<= 1) acci[p] += __shfl_xor(acci[p], off, 64);
    }

    if (ts == 0) {
        const float invT = 1.0f / 512.0f;
        if (g == 0) {
            VSTD(0,0) VSTO(0,0,1) VSTO(1,0,2) VSTO(2,0,3) VSTO(3,0,4)
                      VSTO(4,0,5) VSTO(5,0,6) VSTO(6,0,7)
            VSTD(1,3) VSTO(7,3,4) VSTO(8,3,5) VSTO(9,3,6) VSTO(10,3,7)
            VSTD(2,5) VSTO(11,5,6) VSTO(12,5,7)
            VSTD(3,6) VSTO(13,6,7)
        } else {
            VSTD(0,1) VSTO(0,1,2) VSTO(1,1,3) VSTO(2,1,4) VSTO(3,1,5)
                      VSTO(4,1,6) VSTO(5,1,7)
            VSTD(1,2) VSTO(6,2,3) VSTO(7,2,4) VSTO(8,2,5) VSTO(9,2,6)
                      VSTO(10,2,7)
            VSTD(2,4) VSTO(11,4,5) VSTO(12,4,6) VSTO(13,4,7)
            VSTD(3,7)
        }
    }
    __syncthreads();

    // ---- diag fix: add max(trace,1)*EPS (trace spans both row-groups) ----
    if (tid < 64) {
        const int kq = tid >> 3, mq = tid & 7;
        const float dv = s_V[kq][mq][mq].x;
        float tr = dv;
        #pragma unroll
        for (int off = 1; off < 8; off <<= 1) tr += __shfl_xor(tr, off, 64);
        s_V[kq][mq][mq].x = dv + fmaxf(tr, 1.0f) * 1e-6f;
    }
    __syncthreads();

    // ---- phase B: wave-synchronous, zero barriers, all waves redundant ----
    {
        const int lane = tid & 63;
        const int kp = lane >> 3, mm = lane & 7;
        float vRr[8], vRi[8];
        #pragma unroll
        for (int n = 0; n < 8; ++n) {
            const float2 V = s_V[kp][mm][n];
            vRr[n] = V.x; vRi[n] = V.y;
        }
        const float2 Q0 = s_Q[kp][mm];
        float qre = Q0.x, qim = Q0.y;

        #pragma unroll
        for (int step = 0; step < 16; ++step) {
            const int kk = step & 7;
            float qnr[8], qni[8];
            #pragma unroll
            for (int n = 0; n < 8; ++n) {
                qnr[n] = __shfl(qre, (kk<<3)+n, 64);
                qni[n] = __shfl(qim, (kk<<3)+n, 64);
            }
            const float qmr = __shfl(qre, (kk<<3)+mm, 64);
            const float qmi = __shfl(qim, (kk<<3)+mm, 64);

            float vqr = 0.f, vqi = 0.f;
            #pragma unroll
            for (int n = 0; n < 8; ++n) {
                vqr += vRr[n]*qnr[n] + vRi[n]*qni[n];   // V * conj(q)
                vqi += vRi[n]*qnr[n] - vRr[n]*qni[n];
            }
            float p   = qmr*vqr - qmi*vqi;              // Re(q_m * Vq_m)
            float tre = qre*vqr - qim*vqi;              // Q_own * Vq_own
            float tim = qre*vqi + qim*vqr;
            #pragma unroll
            for (int off = 1; off < 8; off <<= 1) {
                p   += __shfl_xor(p,   off, 64);
                tre += __shfl_xor(tre, off, 64);
                tim += __shfl_xor(tim, off, 64);
            }
            const float qvq = fmaxf(p, 1e-6f);
            float vr_, vi_;
            if (kp == kk) { vr_ = 1.0f - rsqrtf(qvq); vi_ = 0.f; }
            else { const float inv = 1.0f / qvq; vr_ = tre*inv; vi_ = tim*inv; }
            qre -= vr_*qmr - vi_*qmi;
            qim -= vr_*qmi + vi_*qmr;
        }

        if (tid < 64) {
            s_Q[kp][mm] = make_float2(qre, qim);
            if (qmode == 2) {
                g_out[(size_t)bf*128 + tid*2]     = qre;
                g_out[(size_t)bf*128 + tid*2 + 1] = qim;
            } else {
                g_out[(size_t)bf*64 + tid] = qre;
            }
        }
    }
    __syncthreads();

    // ---- phase C: xt = |Q x|^2. Lane-stride-1 t => 2-way LDS access (free),
    //      scalar stores fully coalesced (round 5's 4-t float4 pattern was an
    //      8-way bank conflict: 5.2M SQ_LDS_BANK_CONFLICT). ----
    float lsum = 0.f;
    float* out_xt = g_out + xt_off;
    {
        const int w    = tid >> 6;     // wave 0..3 owns m = 2w, 2w+1
        const int lane = tid & 63;
        #pragma unroll
        for (int mi = 0; mi < 2; ++mi) {
            const int m = (w << 1) + mi;
            float2 qv[8];
            #pragma unroll
            for (int n = 0; n < 8; ++n) qv[n] = s_Q[m][n];   // broadcast reads
            #pragma unroll
            for (int i = 0; i < 8; ++i) {
                const int t = lane + (i << 6);
                float qxr = 0.f, qxi = 0.f;
                #pragma unroll
                for (int n = 0; n < 8; ++n) {
                    const float2 xv = s_x[n][t];
                    qxr += qv[n].x*xv.x - qv[n].y*xv.y;
                    qxi += qv[n].x*xv.y + qv[n].y*xv.x;
                }
                const float pw = qxr*qxr + qxi*qxi;
                out_xt[base + (m << 9) + t] = pw;
                lsum += pw;
            }
        }
    }
    #pragma unroll
    for (int off = 32; off >= 1; off >>= 1) lsum += __shfl_xor(lsum, off, 64);
    if ((tid & 63) == 0) s_part[tid >> 6] = lsum;
    __syncthreads();
    if (tid == 0) d_partials[bf] = s_part[0] + s_part[1] + s_part[2] + s_part[3];
}

__global__ __launch_bounds__(256) void iss_scale()
{
    const int b = blockIdx.x, tid = threadIdx.x;
    __shared__ float sp[4];
    float s = 0.f;
    for (int i = tid; i < 513; i += 256) s += d_partials[b*513 + i];
    #pragma unroll
    for (int off = 32; off >= 1; off >>= 1) s += __shfl_xor(s, off, 64);
    if ((tid & 63) == 0) sp[tid >> 6] = s;
    __syncthreads();
    if (tid == 0) d_scales[b] = (sp[0]+sp[1]+sp[2]+sp[3]) / (513.0f * 8.0f * 512.0f);
}

__global__ __launch_bounds__(256) void iss_norm(
    float* __restrict__ g_out,
    const int nq4,     // Q region in float4s  (= xt_off/4)
    const int qb4,     // float4s per batch in Q region
    const int nt4)     // total float4s (= out_size/4)
{
    float4* o4 = (float4*)g_out;
    for (int i = blockIdx.x*256 + threadIdx.x; i < nt4; i += gridDim.x*256) {
        float s;
        if (i < nq4) {
            const int b = i / qb4;
            s = rsqrtf(fmaxf(d_scales[b], 1e-6f));
        } else {
            const int j = i - nq4;
            const int b = j / 525312;          // xt float4s per batch
            s = 1.0f / d_scales[b];
        }
        float4 v = o4[i];
        v.x *= s; v.y *= s; v.z *= s; v.w *= s;
        o4[i] = v;
    }
}

extern "C" void kernel_launch(void* const* d_in, const int* in_sizes, int n_in,
                              void* d_out, int out_size, void* d_ws, size_t ws_size,
                              hipStream_t stream) {
    const float* r   = (const float*)d_in[0];
    const float* xre = (const float*)d_in[1];
    const float* xim = (const float*)d_in[2];
    const float* Qre = (const float*)d_in[3];
    const float* Qim = (const float*)d_in[4];
    float* out = (float*)d_out;

    const int q_floats = out_size - XT_FLOATS;
    const int qmode  = (q_floats >= 525312) ? 2 : 1;
    const int xt_off = (qmode == 2) ? 525312 : 262656;
    const int nq4 = xt_off / 4;
    const int qb4 = xt_off / (4 * 8);
    const int nt4 = nq4 + XT_FLOATS / 4;

    iss_main <<<NBF, 256, 0, stream>>>(r, xre, xim, Qre, Qim, out, qmode, xt_off);
    iss_scale<<<8,   256, 0, stream>>>();
    iss_norm <<<4096,256, 0, stream>>>(out, nq4, qb4, nt4);
}

// Round 8
// 1328.225 us; speedup vs baseline: 1.4591x; 1.3563x over previous
//
#include <hip/hip_runtime.h>
#include <math.h>

#define NBF 4104             // B*F = 8*513
#define XT_FLOATS 16809984   // 8*513*8*512

// Static device scratch; fully overwritten before read each call -> deterministic.
__device__ float d_partials[NBF];
__device__ float d_scales[8];

// Phase-A macros. All accumulators are PLAIN LOCALS with compile-time indices.
#define DIAG(Q,M)    yr = rw*xv[M].x; yi = rw*xv[M].y; \
                     accd[Q] += yr*xv[M].x + yi*xv[M].y;
#define CROSS(P,M,N) accr[P] += yr*xv[N].x + yi*xv[N].y; \
                     acci[P] += yi*xv[N].x - yr*xv[N].y;
#define VSTD(Q,M)    s_V[k][M][M] = make_float2(accd[Q]*invT, 0.f);
#define VSTO(P,M,N)  { const float vr=accr[P]*invT, vi=acci[P]*invT; \
                       s_V[k][M][N] = make_float2(vr,  vi);          \
                       s_V[k][N][M] = make_float2(vr, -vi); }

// EMPIRICAL launch_bounds law on this compiler: VGPR cap = 256 / arg2.
//   arg=4 -> 64  (rounds 4,7: catastrophic spill, ~6 GB scratch traffic)
//   arg=3 -> 85  (round 6)
//   arg=2 -> 128 (this round: >= ~110 natural need, 1.2x margin, no spill)
// VGPR<=128 gives 16 waves/CU; LDS 38.4KB x 4 blocks = 153.6 <= 160 KB -> 4 blocks/CU.
__global__ __launch_bounds__(256, 2) void iss_main(
    const float* __restrict__ g_r,
    const float* __restrict__ g_xre,
    const float* __restrict__ g_xim,
    const float* __restrict__ g_Qre,
    const float* __restrict__ g_Qim,
    float* __restrict__ g_out,
    const int qmode,        // 2 = interleaved re,im pairs; 1 = real part only
    const int xt_off)       // float offset where the xt region begins
{
    __shared__ float2 s_x[8][512];     // packed (re,im), 32 KB
    __shared__ float2 s_V[8][8][9];    // padded row stride
    __shared__ float2 s_Q[8][8];
    __shared__ float  s_part[4];

    const int tid = threadIdx.x;
    const int bf  = blockIdx.x;
    const size_t base = (size_t)bf * 4096;

    // ---- stage x into packed LDS (float4 global loads, coalesced); Q into s_Q ----
    {
        const float4* xr4 = (const float4*)(g_xre + base);
        const float4* xi4 = (const float4*)(g_xim + base);
        float4* sx4 = (float4*)&s_x[0][0];
        #pragma unroll
        for (int i = 0; i < 4; ++i) {
            const int idx = tid + (i << 8);
            const float4 xr = xr4[idx], xi = xi4[idx];
            sx4[2*idx]   = make_float4(xr.x, xi.x, xr.y, xi.y);
            sx4[2*idx+1] = make_float4(xr.z, xi.z, xr.w, xi.w);
        }
        if (tid < 64)
            s_Q[tid>>3][tid&7] = make_float2(g_Qre[(size_t)bf*64 + tid],
                                             g_Qim[(size_t)bf*64 + tid]);
    }
    __syncthreads();

    // ---- phase A: V[k] = (1/T) sum_t max(r,1e-3) x x^H, row-group split ----
    // 16 lanes per (g,k) group; g0 owns rows {0,3,5,6}, g1 rows {1,2,4,7}
    // (14 off-diagonal complex entries + 4 diagonals each).
    const int ts = tid & 15;
    const int k  = (tid >> 4) & 7;
    const int g  = tid >> 7;          // wave-uniform

    float accd[4] = {0,0,0,0};
    float accr[14], acci[14];
    #pragma unroll
    for (int p = 0; p < 14; ++p) { accr[p] = 0.f; acci[p] = 0.f; }

    {
        // prefetch all 32 r values (stride 16 floats) -> global latency amortized
        float rbuf[32];
        const float* rrow = g_r + base + (k << 9) + ts;
        #pragma unroll
        for (int i = 0; i < 32; ++i) rbuf[i] = rrow[i << 4];

        if (g == 0) {
            #pragma unroll
            for (int i = 0; i < 32; ++i) {
                const int t = ts + (i << 4);
                const float rw = fmaxf(rbuf[i], 1e-3f);
                float2 xv[8];
                #pragma unroll
                for (int n = 0; n < 8; ++n) xv[n] = s_x[n][t];
                float yr, yi;
                DIAG(0,0) CROSS(0,0,1) CROSS(1,0,2) CROSS(2,0,3) CROSS(3,0,4)
                          CROSS(4,0,5) CROSS(5,0,6) CROSS(6,0,7)
                DIAG(1,3) CROSS(7,3,4) CROSS(8,3,5) CROSS(9,3,6) CROSS(10,3,7)
                DIAG(2,5) CROSS(11,5,6) CROSS(12,5,7)
                DIAG(3,6) CROSS(13,6,7)
            }
        } else {
            #pragma unroll
            for (int i = 0; i < 32; ++i) {
                const int t = ts + (i << 4);
                const float rw = fmaxf(rbuf[i], 1e-3f);
                float2 xv[8];
                #pragma unroll
                for (int n = 0; n < 8; ++n) xv[n] = s_x[n][t];
                float yr, yi;
                DIAG(0,1) CROSS(0,1,2) CROSS(1,1,3) CROSS(2,1,4) CROSS(3,1,5)
                          CROSS(4,1,6) CROSS(5,1,7)
                DIAG(1,2) CROSS(6,2,3) CROSS(7,2,4) CROSS(8,2,5) CROSS(9,2,6)
                          CROSS(10,2,7)
                DIAG(2,4) CROSS(11,4,5) CROSS(12,4,6) CROSS(13,4,7)
                DIAG(3,7)
            }
        }
    }

    // reduce across the 16 lanes sharing (g,k): xor offsets 1..8 stay in-group
    #pragma unroll
    for (int q = 0; q < 4; ++q) {
        #pragma unroll
        for (int off = 1; off < 16; off <<= 1) accd[q] += __shfl_xor(accd[q], off, 64);
    }
    #pragma unroll
    for (int p = 0; p < 14; ++p) {
        #pragma unroll
        for (int off = 1; off < 16; off <<= 1) accr[p] += __shfl_xor(accr[p], off, 64);
        #pragma unroll
        for (int off = 1; off < 16; off <<= 1) acci[p] += __shfl_xor(acci[p], off, 64);
    }

    if (ts == 0) {
        const float invT = 1.0f / 512.0f;
        if (g == 0) {
            VSTD(0,0) VSTO(0,0,1) VSTO(1,0,2) VSTO(2,0,3) VSTO(3,0,4)
                      VSTO(4,0,5) VSTO(5,0,6) VSTO(6,0,7)
            VSTD(1,3) VSTO(7,3,4) VSTO(8,3,5) VSTO(9,3,6) VSTO(10,3,7)
            VSTD(2,5) VSTO(11,5,6) VSTO(12,5,7)
            VSTD(3,6) VSTO(13,6,7)
        } else {
            VSTD(0,1) VSTO(0,1,2) VSTO(1,1,3) VSTO(2,1,4) VSTO(3,1,5)
                      VSTO(4,1,6) VSTO(5,1,7)
            VSTD(1,2) VSTO(6,2,3) VSTO(7,2,4) VSTO(8,2,5) VSTO(9,2,6)
                      VSTO(10,2,7)
            VSTD(2,4) VSTO(11,4,5) VSTO(12,4,6) VSTO(13,4,7)
            VSTD(3,7)
        }
    }
    __syncthreads();

    // ---- diag fix: add max(trace,1)*EPS (trace spans both row-groups) ----
    if (tid < 64) {
        const int kq = tid >> 3, mq = tid & 7;
        const float dv = s_V[kq][mq][mq].x;
        float tr = dv;
        #pragma unroll
        for (int off = 1; off < 8; off <<= 1) tr += __shfl_xor(tr, off, 64);
        s_V[kq][mq][mq].x = dv + fmaxf(tr, 1.0f) * 1e-6f;
    }
    __syncthreads();

    // ---- phase B: wave-synchronous, zero barriers, all waves redundant ----
    {
        const int lane = tid & 63;
        const int kp = lane >> 3, mm = lane & 7;
        float vRr[8], vRi[8];
        #pragma unroll
        for (int n = 0; n < 8; ++n) {
            const float2 V = s_V[kp][mm][n];
            vRr[n] = V.x; vRi[n] = V.y;
        }
        const float2 Q0 = s_Q[kp][mm];
        float qre = Q0.x, qim = Q0.y;

        #pragma unroll
        for (int step = 0; step < 16; ++step) {
            const int kk = step & 7;
            float qnr[8], qni[8];
            #pragma unroll
            for (int n = 0; n < 8; ++n) {
                qnr[n] = __shfl(qre, (kk<<3)+n, 64);
                qni[n] = __shfl(qim, (kk<<3)+n, 64);
            }
            const float qmr = __shfl(qre, (kk<<3)+mm, 64);
            const float qmi = __shfl(qim, (kk<<3)+mm, 64);

            float vqr = 0.f, vqi = 0.f;
            #pragma unroll
            for (int n = 0; n < 8; ++n) {
                vqr += vRr[n]*qnr[n] + vRi[n]*qni[n];   // V * conj(q)
                vqi += vRi[n]*qnr[n] - vRr[n]*qni[n];
            }
            float p   = qmr*vqr - qmi*vqi;              // Re(q_m * Vq_m)
            float tre = qre*vqr - qim*vqi;              // Q_own * Vq_own
            float tim = qre*vqi + qim*vqr;
            #pragma unroll
            for (int off = 1; off < 8; off <<= 1) {
                p   += __shfl_xor(p,   off, 64);
                tre += __shfl_xor(tre, off, 64);
                tim += __shfl_xor(tim, off, 64);
            }
            const float qvq = fmaxf(p, 1e-6f);
            float vr_, vi_;
            if (kp == kk) { vr_ = 1.0f - rsqrtf(qvq); vi_ = 0.f; }
            else { const float inv = 1.0f / qvq; vr_ = tre*inv; vi_ = tim*inv; }
            qre -= vr_*qmr - vi_*qmi;
            qim -= vr_*qmi + vi_*qmr;
        }

        if (tid < 64) {
            s_Q[kp][mm] = make_float2(qre, qim);
            if (qmode == 2) {
                g_out[(size_t)bf*128 + tid*2]     = qre;
                g_out[(size_t)bf*128 + tid*2 + 1] = qim;
            } else {
                g_out[(size_t)bf*64 + tid] = qre;
            }
        }
    }
    __syncthreads();

    // ---- phase C: xt = |Q x|^2, lane-stride-1 t, scalar coalesced stores ----
    float lsum = 0.f;
    float* out_xt = g_out + xt_off;
    {
        const int w    = tid >> 6;     // wave 0..3 owns m = 2w, 2w+1
        const int lane = tid & 63;
        #pragma unroll
        for (int mi = 0; mi < 2; ++mi) {
            const int m = (w << 1) + mi;
            float2 qv[8];
            #pragma unroll
            for (int n = 0; n < 8; ++n) qv[n] = s_Q[m][n];   // broadcast reads
            #pragma unroll
            for (int i = 0; i < 8; ++i) {
                const int t = lane + (i << 6);
                float qxr = 0.f, qxi = 0.f;
                #pragma unroll
                for (int n = 0; n < 8; ++n) {
                    const float2 xv = s_x[n][t];
                    qxr += qv[n].x*xv.x - qv[n].y*xv.y;
                    qxi += qv[n].x*xv.y + qv[n].y*xv.x;
                }
                const float pw = qxr*qxr + qxi*qxi;
                out_xt[base + (m << 9) + t] = pw;
                lsum += pw;
            }
        }
    }
    #pragma unroll
    for (int off = 32; off >= 1; off >>= 1) lsum += __shfl_xor(lsum, off, 64);
    if ((tid & 63) == 0) s_part[tid >> 6] = lsum;
    __syncthreads();
    if (tid == 0) d_partials[bf] = s_part[0] + s_part[1] + s_part[2] + s_part[3];
}

__global__ __launch_bounds__(256) void iss_scale()
{
    const int b = blockIdx.x, tid = threadIdx.x;
    __shared__ float sp[4];
    float s = 0.f;
    for (int i = tid; i < 513; i += 256) s += d_partials[b*513 + i];
    #pragma unroll
    for (int off = 32; off >= 1; off >>= 1) s += __shfl_xor(s, off, 64);
    if ((tid & 63) == 0) sp[tid >> 6] = s;
    __syncthreads();
    if (tid == 0) d_scales[b] = (sp[0]+sp[1]+sp[2]+sp[3]) / (513.0f * 8.0f * 512.0f);
}

__global__ __launch_bounds__(256) void iss_norm(
    float* __restrict__ g_out,
    const int nq4,     // Q region in float4s  (= xt_off/4)
    const int qb4,     // float4s per batch in Q region
    const int nt4)     // total float4s (= out_size/4)
{
    float4* o4 = (float4*)g_out;
    for (int i = blockIdx.x*256 + threadIdx.x; i < nt4; i += gridDim.x*256) {
        float s;
        if (i < nq4) {
            const int b = i / qb4;
            s = rsqrtf(fmaxf(d_scales[b], 1e-6f));
        } else {
            const int j = i - nq4;
            const int b = j / 525312;          // xt float4s per batch
            s = 1.0f / d_scales[b];
        }
        float4 v = o4[i];
        v.x *= s; v.y *= s; v.z *= s; v.w *= s;
        o4[i] = v;
    }
}

extern "C" void kernel_launch(void* const* d_in, const int* in_sizes, int n_in,
                              void* d_out, int out_size, void* d_ws, size_t ws_size,
                              hipStream_t stream) {
    const float* r   = (const float*)d_in[0];
    const float* xre = (const float*)d_in[1];
    const float* xim = (const float*)d_in[2];
    const float* Qre = (const float*)d_in[3];
    const float* Qim = (const float*)d_in[4];
    float* out = (float*)d_out;

    const int q_floats = out_size - XT_FLOATS;
    const int qmode  = (q_floats >= 525312) ? 2 : 1;
    const int xt_off = (qmode == 2) ? 525312 : 262656;
    const int nq4 = xt_off / 4;
    const int qb4 = xt_off / (4 * 8);
    const int nt4 = nq4 + XT_FLOATS / 4;

    iss_main <<<NBF, 256, 0, stream>>>(r, xre, xim, Qre, Qim, out, qmode, xt_off);
    iss_scale<<<8,   256, 0, stream>>>();
    iss_norm <<<4096,256, 0, stream>>>(out, nq4, qb4, nt4);
}

// Round 9
// 308.864 us; speedup vs baseline: 6.2745x; 4.3004x over previous
//
#include <hip/hip_runtime.h>
#include <math.h>

#define NBF 4104             // B*F = 8*513
#define XT_FLOATS 16809984   // 8*513*8*512

// Static device scratch; fully overwritten before read each call -> deterministic.
__device__ float d_partials[NBF];
__device__ float d_scales[8];

// Phase-A macros. All accumulators are PLAIN LOCALS with compile-time indices.
#define DIAG(Q,M)    yr = rw*xv[M].x; yi = rw*xv[M].y; \
                     accd[Q] += yr*xv[M].x + yi*xv[M].y;
#define CROSS(P,M,N) accr[P] += yr*xv[N].x + yi*xv[N].y; \
                     acci[P] += yi*xv[N].x - yr*xv[N].y;
#define VSTD(Q,M)    s_V[k][M][M] = make_float2(accd[Q]*invT, 0.f);
#define VSTO(P,M,N)  { const float vr=accr[P]*invT, vi=acci[P]*invT; \
                       s_V[k][M][N] = make_float2(vr,  vi);          \
                       s_V[k][N][M] = make_float2(vr, -vi); }

// launch_bounds law (empirical, this compiler): VGPR cap = 256/arg2.
//   arg4->64 (r4,r7: spill disaster), arg3->85 (r6: spill), arg2->128.
// Round 8 spilled at 128 because rbuf[32]+unroll kept ~150 live. This round
// chunks r-prefetch to 8 (live ~= 32 acc + 8 rbuf + 16 xv + addr ~= 90),
// a real 1.4x margin under the 128 cap.
__global__ __launch_bounds__(256, 2) void iss_main(
    const float* __restrict__ g_r,
    const float* __restrict__ g_xre,
    const float* __restrict__ g_xim,
    const float* __restrict__ g_Qre,
    const float* __restrict__ g_Qim,
    float* __restrict__ g_out,
    const int qmode,        // 2 = interleaved re,im pairs; 1 = real part only
    const int xt_off)       // float offset where the xt region begins
{
    __shared__ float2 s_x[8][512];     // packed (re,im), 32 KB
    __shared__ float2 s_V[8][8][9];    // padded row stride
    __shared__ float2 s_Q[8][8];
    __shared__ float  s_part[4];

    const int tid = threadIdx.x;
    const int bf  = blockIdx.x;
    const size_t base = (size_t)bf * 4096;

    // ---- stage x into packed LDS (float4 global loads, coalesced); Q into s_Q ----
    {
        const float4* xr4 = (const float4*)(g_xre + base);
        const float4* xi4 = (const float4*)(g_xim + base);
        float4* sx4 = (float4*)&s_x[0][0];
        #pragma unroll
        for (int i = 0; i < 4; ++i) {
            const int idx = tid + (i << 8);
            const float4 xr = xr4[idx], xi = xi4[idx];
            sx4[2*idx]   = make_float4(xr.x, xi.x, xr.y, xi.y);
            sx4[2*idx+1] = make_float4(xr.z, xi.z, xr.w, xi.w);
        }
        if (tid < 64)
            s_Q[tid>>3][tid&7] = make_float2(g_Qre[(size_t)bf*64 + tid],
                                             g_Qim[(size_t)bf*64 + tid]);
    }
    __syncthreads();

    // ---- phase A: V[k] = (1/T) sum_t max(r,1e-3) x x^H, row-group split ----
    // 16 lanes per (g,k) group; g0 owns rows {0,3,5,6}, g1 rows {1,2,4,7}.
    const int ts = tid & 15;
    const int k  = (tid >> 4) & 7;
    const int g  = tid >> 7;          // wave-uniform

    float accd[4] = {0,0,0,0};
    float accr[14], acci[14];
    #pragma unroll
    for (int p = 0; p < 14; ++p) { accr[p] = 0.f; acci[p] = 0.f; }

    {
        const float* rrow = g_r + base + (k << 9) + ts;
        #pragma unroll
        for (int c = 0; c < 4; ++c) {
            // 8 r-loads per chunk, consumed immediately (keeps live set small;
            // r8's rbuf[32] pushed live regs past the 128 cap -> 1 GB spill)
            float rb[8];
            #pragma unroll
            for (int i = 0; i < 8; ++i) rb[i] = rrow[((c << 3) + i) << 4];

            if (g == 0) {
                #pragma unroll
                for (int i = 0; i < 8; ++i) {
                    const int t = ts + (((c << 3) + i) << 4);
                    const float rw = fmaxf(rb[i], 1e-3f);
                    float2 xv[8];
                    #pragma unroll
                    for (int n = 0; n < 8; ++n) xv[n] = s_x[n][t];
                    float yr, yi;
                    DIAG(0,0) CROSS(0,0,1) CROSS(1,0,2) CROSS(2,0,3) CROSS(3,0,4)
                              CROSS(4,0,5) CROSS(5,0,6) CROSS(6,0,7)
                    DIAG(1,3) CROSS(7,3,4) CROSS(8,3,5) CROSS(9,3,6) CROSS(10,3,7)
                    DIAG(2,5) CROSS(11,5,6) CROSS(12,5,7)
                    DIAG(3,6) CROSS(13,6,7)
                }
            } else {
                #pragma unroll
                for (int i = 0; i < 8; ++i) {
                    const int t = ts + (((c << 3) + i) << 4);
                    const float rw = fmaxf(rb[i], 1e-3f);
                    float2 xv[8];
                    #pragma unroll
                    for (int n = 0; n < 8; ++n) xv[n] = s_x[n][t];
                    float yr, yi;
                    DIAG(0,1) CROSS(0,1,2) CROSS(1,1,3) CROSS(2,1,4) CROSS(3,1,5)
                              CROSS(4,1,6) CROSS(5,1,7)
                    DIAG(1,2) CROSS(6,2,3) CROSS(7,2,4) CROSS(8,2,5) CROSS(9,2,6)
                              CROSS(10,2,7)
                    DIAG(2,4) CROSS(11,4,5) CROSS(12,4,6) CROSS(13,4,7)
                    DIAG(3,7)
                }
            }
        }
    }

    // reduce across the 16 lanes sharing (g,k): xor offsets 1..8 stay in-group
    #pragma unroll
    for (int q = 0; q < 4; ++q) {
        #pragma unroll
        for (int off = 1; off < 16; off <<= 1) accd[q] += __shfl_xor(accd[q], off, 64);
    }
    #pragma unroll
    for (int p = 0; p < 14; ++p) {
        #pragma unroll
        for (int off = 1; off < 16; off <<= 1) accr[p] += __shfl_xor(accr[p], off, 64);
        #pragma unroll
        for (int off = 1; off < 16; off <<= 1) acci[p] += __shfl_xor(acci[p], off, 64);
    }

    if (ts == 0) {
        const float invT = 1.0f / 512.0f;
        if (g == 0) {
            VSTD(0,0) VSTO(0,0,1) VSTO(1,0,2) VSTO(2,0,3) VSTO(3,0,4)
                      VSTO(4,0,5) VSTO(5,0,6) VSTO(6,0,7)
            VSTD(1,3) VSTO(7,3,4) VSTO(8,3,5) VSTO(9,3,6) VSTO(10,3,7)
            VSTD(2,5) VSTO(11,5,6) VSTO(12,5,7)
            VSTD(3,6) VSTO(13,6,7)
        } else {
            VSTD(0,1) VSTO(0,1,2) VSTO(1,1,3) VSTO(2,1,4) VSTO(3,1,5)
                      VSTO(4,1,6) VSTO(5,1,7)
            VSTD(1,2) VSTO(6,2,3) VSTO(7,2,4) VSTO(8,2,5) VSTO(9,2,6)
                      VSTO(10,2,7)
            VSTD(2,4) VSTO(11,4,5) VSTO(12,4,6) VSTO(13,4,7)
            VSTD(3,7)
        }
    }
    __syncthreads();

    // ---- diag fix: add max(trace,1)*EPS (trace spans both row-groups) ----
    if (tid < 64) {
        const int kq = tid >> 3, mq = tid & 7;
        const float dv = s_V[kq][mq][mq].x;
        float tr = dv;
        #pragma unroll
        for (int off = 1; off < 8; off <<= 1) tr += __shfl_xor(tr, off, 64);
        s_V[kq][mq][mq].x = dv + fmaxf(tr, 1.0f) * 1e-6f;
    }
    __syncthreads();

    // ---- phase B: wave-synchronous, zero barriers, all waves redundant ----
    {
        const int lane = tid & 63;
        const int kp = lane >> 3, mm = lane & 7;
        float vRr[8], vRi[8];
        #pragma unroll
        for (int n = 0; n < 8; ++n) {
            const float2 V = s_V[kp][mm][n];
            vRr[n] = V.x; vRi[n] = V.y;
        }
        const float2 Q0 = s_Q[kp][mm];
        float qre = Q0.x, qim = Q0.y;

        #pragma unroll
        for (int step = 0; step < 16; ++step) {
            const int kk = step & 7;
            float qnr[8], qni[8];
            #pragma unroll
            for (int n = 0; n < 8; ++n) {
                qnr[n] = __shfl(qre, (kk<<3)+n, 64);
                qni[n] = __shfl(qim, (kk<<3)+n, 64);
            }
            const float qmr = __shfl(qre, (kk<<3)+mm, 64);
            const float qmi = __shfl(qim, (kk<<3)+mm, 64);

            float vqr = 0.f, vqi = 0.f;
            #pragma unroll
            for (int n = 0; n < 8; ++n) {
                vqr += vRr[n]*qnr[n] + vRi[n]*qni[n];   // V * conj(q)
                vqi += vRi[n]*qnr[n] - vRr[n]*qni[n];
            }
            float p   = qmr*vqr - qmi*vqi;              // Re(q_m * Vq_m)
            float tre = qre*vqr - qim*vqi;              // Q_own * Vq_own
            float tim = qre*vqi + qim*vqr;
            #pragma unroll
            for (int off = 1; off < 8; off <<= 1) {
                p   += __shfl_xor(p,   off, 64);
                tre += __shfl_xor(tre, off, 64);
                tim += __shfl_xor(tim, off, 64);
            }
            const float qvq = fmaxf(p, 1e-6f);
            float vr_, vi_;
            if (kp == kk) { vr_ = 1.0f - rsqrtf(qvq); vi_ = 0.f; }
            else { const float inv = 1.0f / qvq; vr_ = tre*inv; vi_ = tim*inv; }
            qre -= vr_*qmr - vi_*qmi;
            qim -= vr_*qmi + vi_*qmr;
        }

        if (tid < 64) {
            s_Q[kp][mm] = make_float2(qre, qim);
            if (qmode == 2) {
                g_out[(size_t)bf*128 + tid*2]     = qre;
                g_out[(size_t)bf*128 + tid*2 + 1] = qim;
            } else {
                g_out[(size_t)bf*64 + tid] = qre;
            }
        }
    }
    __syncthreads();

    // ---- phase C: xt = |Q x|^2, lane-stride-1 t, scalar coalesced stores ----
    float lsum = 0.f;
    float* out_xt = g_out + xt_off;
    {
        const int w    = tid >> 6;     // wave 0..3 owns m = 2w, 2w+1
        const int lane = tid & 63;
        #pragma unroll
        for (int mi = 0; mi < 2; ++mi) {
            const int m = (w << 1) + mi;
            float2 qv[8];
            #pragma unroll
            for (int n = 0; n < 8; ++n) qv[n] = s_Q[m][n];   // broadcast reads
            #pragma unroll
            for (int i = 0; i < 8; ++i) {
                const int t = lane + (i << 6);
                float qxr = 0.f, qxi = 0.f;
                #pragma unroll
                for (int n = 0; n < 8; ++n) {
                    const float2 xv = s_x[n][t];
                    qxr += qv[n].x*xv.x - qv[n].y*xv.y;
                    qxi += qv[n].x*xv.y + qv[n].y*xv.x;
                }
                const float pw = qxr*qxr + qxi*qxi;
                out_xt[base + (m << 9) + t] = pw;
                lsum += pw;
            }
        }
    }
    #pragma unroll
    for (int off = 32; off >= 1; off >>= 1) lsum += __shfl_xor(lsum, off, 64);
    if ((tid & 63) == 0) s_part[tid >> 6] = lsum;
    __syncthreads();
    if (tid == 0) d_partials[bf] = s_part[0] + s_part[1] + s_part[2] + s_part[3];
}

__global__ __launch_bounds__(256) void iss_scale()
{
    const int b = blockIdx.x, tid = threadIdx.x;
    __shared__ float sp[4];
    float s = 0.f;
    for (int i = tid; i < 513; i += 256) s += d_partials[b*513 + i];
    #pragma unroll
    for (int off = 32; off >= 1; off >>= 1) s += __shfl_xor(s, off, 64);
    if ((tid & 63) == 0) sp[tid >> 6] = s;
    __syncthreads();
    if (tid == 0) d_scales[b] = (sp[0]+sp[1]+sp[2]+sp[3]) / (513.0f * 8.0f * 512.0f);
}

__global__ __launch_bounds__(256) void iss_norm(
    float* __restrict__ g_out,
    const int nq4,     // Q region in float4s  (= xt_off/4)
    const int qb4,     // float4s per batch in Q region
    const int nt4)     // total float4s (= out_size/4)
{
    float4* o4 = (float4*)g_out;
    for (int i = blockIdx.x*256 + threadIdx.x; i < nt4; i += gridDim.x*256) {
        float s;
        if (i < nq4) {
            const int b = i / qb4;
            s = rsqrtf(fmaxf(d_scales[b], 1e-6f));
        } else {
            const int j = i - nq4;
            const int b = j / 525312;          // xt float4s per batch
            s = 1.0f / d_scales[b];
        }
        float4 v = o4[i];
        v.x *= s; v.y *= s; v.z *= s; v.w *= s;
        o4[i] = v;
    }
}

extern "C" void kernel_launch(void* const* d_in, const int* in_sizes, int n_in,
                              void* d_out, int out_size, void* d_ws, size_t ws_size,
                              hipStream_t stream) {
    const float* r   = (const float*)d_in[0];
    const float* xre = (const float*)d_in[1];
    const float* xim = (const float*)d_in[2];
    const float* Qre = (const float*)d_in[3];
    const float* Qim = (const float*)d_in[4];
    float* out = (float*)d_out;

    const int q_floats = out_size - XT_FLOATS;
    const int qmode  = (q_floats >= 525312) ? 2 : 1;
    const int xt_off = (qmode == 2) ? 525312 : 262656;
    const int nq4 = xt_off / 4;
    const int qb4 = xt_off / (4 * 8);
    const int nt4 = nq4 + XT_FLOATS / 4;

    iss_main <<<NBF, 256, 0, stream>>>(r, xre, xim, Qre, Qim, out, qmode, xt_off);
    iss_scale<<<8,   256, 0, stream>>>();
    iss_norm <<<4096,256, 0, stream>>>(out, nq4, qb4, nt4);
}